// Round 7
// baseline (368.907 us; speedup 1.0000x reference)
//
#include <hip/hip_runtime.h>

#define NV 512
#define BV 8
#define KSEL 26163
#define NNv (NV*NV)          // 262144
#define BKv (BV*KSEL)        // 209304
#define CAPB 32768
#define DELTA 1e-4f          // approx-score error bound (worst-case ~2e-5)

typedef unsigned int u32;
typedef __attribute__((ext_vector_type(2))) float f32x2;
typedef __attribute__((ext_vector_type(4))) float f32x4;
typedef __attribute__((ext_vector_type(4))) u32 u32x4;
typedef __attribute__((ext_vector_type(8))) _Float16 f16x8;

__device__ __forceinline__ f32x2 pk_add(f32x2 a, f32x2 b) {
    f32x2 d; asm("v_pk_add_f32 %0, %1, %2" : "=v"(d) : "v"(a), "v"(b)); return d;
}
__device__ __forceinline__ f32x2 pk_fma(f32x2 a, f32x2 b, f32x2 c) {
    f32x2 d; asm("v_pk_fma_f32 %0, %1, %2, %3" : "=v"(d) : "v"(a), "v"(b), "v"(c)); return d;
}
__device__ __forceinline__ u32 pkrtz(float a, float b) {
    u32 d; asm("v_cvt_pkrtz_f16_f32 %0, %1, %2" : "=v"(d) : "v"(a), "v"(b)); return d;
}
__device__ __forceinline__ float fast_sigmoid(float z) {
    float e, p;
    asm("v_exp_f32 %0, %1" : "=v"(e) : "v"(-z * 1.44269504f));
    asm("v_rcp_f32 %0, %1" : "=v"(p) : "v"(1.f + e));
    return p;
}

// ---------------- embed: x -> emb -> ai, aj (exact) + ai256, ajb256 ---------
__global__ void __launch_bounds__(256) k_embed(
    const float* __restrict__ x, const float* __restrict__ w_emb,
    const float* __restrict__ b_emb, const float* __restrict__ w_proj,
    const float* __restrict__ b_proj, const float* __restrict__ w1,
    const float* __restrict__ b1,
    float* __restrict__ ai, float* __restrict__ aj,
    float* __restrict__ ai256, float* __restrict__ ajb256) {
    __shared__ float sh[4][64];
    __shared__ float se[4][64];
    const int c = threadIdx.x;        // 0..63
    const int lr = threadIdx.y;       // 0..3
    const int row = blockIdx.x * 4 + lr;
    const float xv = x[row];
    sh[lr][c] = fmaxf(fmaf(xv, w_emb[c], b_emb[c]), 0.f);
    __syncthreads();
    float e = 0.f;
#pragma unroll
    for (int h = 0; h < 64; ++h) e = fmaf(sh[lr][h], w_proj[h * 64 + c], e);
    se[lr][c] = e + b_proj[c];
    __syncthreads();
    float a0 = 0.f, a1 = 0.f;
#pragma unroll
    for (int h = 0; h < 64; ++h) {
        const float ev = se[lr][h];
        a0 = fmaf(ev, w1[h * 64 + c], a0);
        a1 = fmaf(ev, w1[(64 + h) * 64 + c], a1);
    }
    ai[row * 64 + c] = a0;
    aj[row * 64 + c] = a1;
    ai256[row * 64 + c] = a0 * 256.0f;                 // exact (pow2)
    ajb256[row * 64 + c] = (a1 + b1[c]) * 256.0f;
}

// ---------------- fused pair scorer + symmetrize + hist8 + selp8 tail -------
__global__ void __launch_bounds__(256) k_pairs_sym(
    const float* __restrict__ ai256, const float* __restrict__ ajb256,
    const float* __restrict__ w2, const float* __restrict__ b2,
    const float* __restrict__ w3, const float* __restrict__ b3,
    float* __restrict__ probs, u32* __restrict__ hist8,
    u32* __restrict__ done1, u32* __restrict__ c8, u32* __restrict__ rem1) {
    __shared__ float sI[2048];        // ai256 rows I0 (32 x 64)
    __shared__ float sJ[2048];        // ai256 rows J0
    __shared__ float sp1[32 * 33];    // sigma(s(i,j)) at [ii][jj], stride 33
    __shared__ float sp2[32 * 33];    // sigma(s(j,i)) at [ii][jj]
    __shared__ u32 lh[1024];          // 4-replica 256-bin hist (reused for scan)
    __shared__ u32 amLast;
    const int tid = threadIdx.x;
    const int b = blockIdx.y;
    int remb = blockIdx.x, ta = 0;
    while (remb >= 16 - ta) { remb -= 16 - ta; ++ta; }
    const int tb = ta + remb;         // ta <= tb
    const int i0 = ta << 5, j0 = tb << 5;
    {
        const int r = tid >> 3, c8v = (tid & 7) << 3;
        const float* srcI = &ai256[(((b << 9) + i0 + r) << 6) + c8v];
        *(float4*)&sI[(r << 6) + c8v]     = *(const float4*)&srcI[0];
        *(float4*)&sI[(r << 6) + c8v + 4] = *(const float4*)&srcI[4];
        const float* srcJ = &ai256[(((b << 9) + j0 + r) << 6) + c8v];
        *(float4*)&sJ[(r << 6) + c8v]     = *(const float4*)&srcJ[0];
        *(float4*)&sJ[(r << 6) + c8v + 4] = *(const float4*)&srcJ[4];
        lh[tid] = 0; lh[256 + tid] = 0; lh[512 + tid] = 0; lh[768 + tid] = 0;
    }
    const int lane = tid & 63;
    const int lp = lane & 15, lg = lane >> 4;
    const int wave = tid >> 6;
    const int dir = wave >> 1, wc = wave & 1;
    const int colb = (wc << 4) + lp;                 // 0..31 within tile
    const int colg = (dir ? i0 : j0) + colb;         // global col row-index

    alignas(16) float ajr[2][8];
    {
        const float* base = &ajb256[(((b << 9) + colg) << 6) + (lg << 3)];
        *(float4*)&ajr[0][0] = *(const float4*)&base[0];
        *(float4*)&ajr[0][4] = *(const float4*)&base[4];
        *(float4*)&ajr[1][0] = *(const float4*)&base[32];
        *(float4*)&ajr[1][4] = *(const float4*)&base[36];
    }
    f16x8 Ah[2][2], Al[2][2];         // w2^T hi / lo*2048 [ktile][hchunk]
#pragma unroll
    for (int kt = 0; kt < 2; ++kt)
#pragma unroll
        for (int ch = 0; ch < 2; ++ch)
#pragma unroll
            for (int e = 0; e < 8; ++e) {
                const float wv2 = w2[((ch << 5) + (lg << 3) + e) * 32 + (kt << 4) + lp];
                const _Float16 wh = (_Float16)wv2;
                Ah[kt][ch][e] = wh;
                Al[kt][ch][e] = (_Float16)((wv2 - (float)wh) * 2048.0f);
            }
    float b2f[2][4], w3f[2][4];
#pragma unroll
    for (int kt = 0; kt < 2; ++kt)
#pragma unroll
        for (int r = 0; r < 4; ++r) {
            b2f[kt][r] = b2[(kt << 4) + (lg << 2) + r] * 256.0f;
            w3f[kt][r] = w3[(kt << 4) + (lg << 2) + r] * 0.00390625f;
        }
    const float b3v = b3[0];
    __syncthreads();

    const float* __restrict__ sA = dir ? sJ : sI;
    float* __restrict__ spO = dir ? sp2 : sp1;
    const f32x2 CN1 = {-1.f, -1.f};

    for (int r = 0; r < 32; ++r) {
        alignas(16) float ar[2][8];
        *(float4*)&ar[0][0] = *(const float4*)&sA[(r << 6) + (lg << 3)];
        *(float4*)&ar[0][4] = *(const float4*)&sA[(r << 6) + (lg << 3) + 4];
        *(float4*)&ar[1][0] = *(const float4*)&sA[(r << 6) + 32 + (lg << 3)];
        *(float4*)&ar[1][4] = *(const float4*)&sA[(r << 6) + 32 + (lg << 3) + 4];
        alignas(16) u32 hw[2][4], lw[2][4];
#pragma unroll
        for (int c = 0; c < 2; ++c)
#pragma unroll
            for (int e2 = 0; e2 < 4; ++e2) {
                const f32x2 a2 = *(const f32x2*)&ar[c][e2 * 2];
                const f32x2 j2 = *(const f32x2*)&ajr[c][e2 * 2];
                f32x2 u2 = pk_add(a2, j2);
                u2[0] = fmaxf(u2[0], 0.f);
                u2[1] = fmaxf(u2[1], 0.f);
                hw[c][e2] = pkrtz(u2[0], u2[1]);
                f32x2 hif;
                hif[0] = __uint_as_float(__float_as_uint(u2[0]) & 0xFFFFE000u);
                hif[1] = __uint_as_float(__float_as_uint(u2[1]) & 0xFFFFE000u);
                const f32x2 lo = pk_fma(hif, CN1, u2);   // exact residual
                lw[c][e2] = pkrtz(lo[0], lo[1]);
            }
        const f16x8 Bh0 = __builtin_bit_cast(f16x8, *(u32x4*)&hw[0][0]);
        const f16x8 Bh1 = __builtin_bit_cast(f16x8, *(u32x4*)&hw[1][0]);
        const f16x8 Bl0 = __builtin_bit_cast(f16x8, *(u32x4*)&lw[0][0]);
        const f16x8 Bl1 = __builtin_bit_cast(f16x8, *(u32x4*)&lw[1][0]);
        // main acc (scale 2^8): wh*th + wh*tl ; c acc (scale 2^19): wl*th
        f32x4 am0 = {0.f,0.f,0.f,0.f}, am1 = {0.f,0.f,0.f,0.f};
        f32x4 ac0 = {0.f,0.f,0.f,0.f}, ac1 = {0.f,0.f,0.f,0.f};
        am0 = __builtin_amdgcn_mfma_f32_16x16x32_f16(Ah[0][0], Bh0, am0, 0, 0, 0);
        am0 = __builtin_amdgcn_mfma_f32_16x16x32_f16(Ah[0][1], Bh1, am0, 0, 0, 0);
        am0 = __builtin_amdgcn_mfma_f32_16x16x32_f16(Ah[0][0], Bl0, am0, 0, 0, 0);
        am0 = __builtin_amdgcn_mfma_f32_16x16x32_f16(Ah[0][1], Bl1, am0, 0, 0, 0);
        ac0 = __builtin_amdgcn_mfma_f32_16x16x32_f16(Al[0][0], Bh0, ac0, 0, 0, 0);
        ac0 = __builtin_amdgcn_mfma_f32_16x16x32_f16(Al[0][1], Bh1, ac0, 0, 0, 0);
        am1 = __builtin_amdgcn_mfma_f32_16x16x32_f16(Ah[1][0], Bh0, am1, 0, 0, 0);
        am1 = __builtin_amdgcn_mfma_f32_16x16x32_f16(Ah[1][1], Bh1, am1, 0, 0, 0);
        am1 = __builtin_amdgcn_mfma_f32_16x16x32_f16(Ah[1][0], Bl0, am1, 0, 0, 0);
        am1 = __builtin_amdgcn_mfma_f32_16x16x32_f16(Ah[1][1], Bl1, am1, 0, 0, 0);
        ac1 = __builtin_amdgcn_mfma_f32_16x16x32_f16(Al[1][0], Bh0, ac1, 0, 0, 0);
        ac1 = __builtin_amdgcn_mfma_f32_16x16x32_f16(Al[1][1], Bh1, ac1, 0, 0, 0);
        float s = 0.f;
#pragma unroll
        for (int q = 0; q < 4; ++q) {
            const float amc = fmaf(ac0[q], 4.8828125e-4f, am0[q]);   // + c*2^-11
            s = fmaf(fmaxf(amc + b2f[0][q], 0.f), w3f[0][q], s);
        }
#pragma unroll
        for (int q = 0; q < 4; ++q) {
            const float amc = fmaf(ac1[q], 4.8828125e-4f, am1[q]);
            s = fmaf(fmaxf(amc + b2f[1][q], 0.f), w3f[1][q], s);
        }
        s += __shfl_xor(s, 16);
        s += __shfl_xor(s, 32);
        const float p = fast_sigmoid(s + b3v);
        if (lane < 16) {
            if (dir == 0) spO[r * 33 + colb] = p;     // sigma(s(i0+r, j0+colb))
            else          spO[colb * 33 + r] = p;     // sigma(s(j0+r, i0+colb))
        }
    }
    __syncthreads();

    // average, diag-zero, write both tiles, histogram
    {
        const int pr = tid >> 3;              // ii
        const int pc = (tid & 7) << 2;        // jj0
        const int rep = (tid & 3) << 8;
        const bool diag = (ta == tb);
        float4 vo;
        float vq[4];
#pragma unroll
        for (int q = 0; q < 4; ++q) {
            float v = 0.5f * (sp1[pr * 33 + pc + q] + sp2[pr * 33 + pc + q]);
            if (diag && pr == pc + q) v = 0.f;
            vq[q] = v;
            atomicAdd(&lh[rep + (__float_as_uint(v) >> 24)], diag ? 1u : 2u);
        }
        vo.x = vq[0]; vo.y = vq[1]; vo.z = vq[2]; vo.w = vq[3];
        *(float4*)&probs[(((b << 9) + i0 + pr) << 9) + j0 + pc] = vo;
        if (!diag) {
            float4 w4;
            w4.x = 0.5f * (sp1[(pc + 0) * 33 + pr] + sp2[(pc + 0) * 33 + pr]);
            w4.y = 0.5f * (sp1[(pc + 1) * 33 + pr] + sp2[(pc + 1) * 33 + pr]);
            w4.z = 0.5f * (sp1[(pc + 2) * 33 + pr] + sp2[(pc + 2) * 33 + pr]);
            w4.w = 0.5f * (sp1[(pc + 3) * 33 + pr] + sp2[(pc + 3) * 33 + pr]);
            *(float4*)&probs[(((b << 9) + j0 + pr) << 9) + i0 + pc] = w4;
        }
    }
    __syncthreads();
    const u32 sum = lh[tid] + lh[256 + tid] + lh[512 + tid] + lh[768 + tid];
    if (sum) atomicAdd(&hist8[b * 256 + tid], sum);

    // -------- last-block tail: 8-bit select for this batch --------
    __threadfence();
    __syncthreads();
    if (tid == 0) amLast = (atomicAdd(&done1[b], 1u) == 135u) ? 1u : 0u;
    __syncthreads();
    if (!amLast) return;
    __threadfence();
    u32* s = lh;
    s[tid] = hist8[b * 256 + tid];
    __syncthreads();
    for (int off = 1; off < 256; off <<= 1) {
        const u32 v = (tid + off < 256) ? s[tid + off] : 0u;
        __syncthreads();
        s[tid] += v;
        __syncthreads();
    }
    const u32 above = (tid < 255) ? s[tid + 1] : 0u;
    if (s[tid] >= (u32)KSEL && above < (u32)KSEL) {
        c8[b] = (u32)tid;
        rem1[b] = (u32)KSEL - above;
    }
}

// ---------------- 13-bit filtered LDS histogram + sel13 tail ----------------
__global__ void __launch_bounds__(256) k_hist13(
    const float* __restrict__ probs, const u32* __restrict__ c8,
    u32* __restrict__ hist13, u32* __restrict__ done2,
    const u32* __restrict__ rem1, float* __restrict__ thr) {
    __shared__ u32 lh[8192];
    __shared__ u32 amLast;
    const int t = threadIdx.x;
    for (int k = t; k < 8192; k += 256) lh[k] = 0u;
    __syncthreads();
    const int b = blockIdx.y;
    const u32 sel = c8[b];
    const float* Pb = probs + b * NNv;
    const int base = blockIdx.x * 4096 + t;
#pragma unroll
    for (int e = 0; e < 16; ++e) {
        const u32 key = __float_as_uint(Pb[base + e * 256]);
        if ((key >> 24) == sel) atomicAdd(&lh[(key >> 11) & 8191u], 1u);
    }
    __syncthreads();
    for (int k = t; k < 8192; k += 256) {
        const u32 v = lh[k];
        if (v) atomicAdd(&hist13[b * 8192 + k], v);
    }
    // -------- last-block tail: 13-bit select -> thr --------
    __threadfence();
    __syncthreads();
    if (t == 0) amLast = (atomicAdd(&done2[b], 1u) == 63u) ? 1u : 0u;
    __syncthreads();
    if (!amLast) return;
    __threadfence();
    const u32* H = hist13 + b * 8192;
    u32 sum = 0;
    for (int k = 0; k < 32; ++k) sum += H[t * 32 + k];
    __shared__ u32 s[256];
    s[t] = sum;
    __syncthreads();
    for (int off = 1; off < 256; off <<= 1) {   // inclusive suffix sums
        const u32 v = (t + off < 256) ? s[t + off] : 0u;
        __syncthreads();
        s[t] += v;
        __syncthreads();
    }
    const u32 remv = rem1[b];
    const u32 above = (t < 255) ? s[t + 1] : 0u;
    if (s[t] >= remv && above < remv) {
        u32 cum = above;
        int c = 31;
        for (; c >= 0; --c) {
            cum += H[t * 32 + c];
            if (cum >= remv) break;
        }
        const u32 p21 = (c8[b] << 13) | (u32)(t * 32 + c);
        thr[b]     = __uint_as_float(p21 << 11) - 2.f * DELTA;        // Tlo
        thr[8 + b] = __uint_as_float((p21 + 1u) << 11) + 2.f * DELTA; // Thi
    }
}

// ---------------- band collect + per-block hi counts ------------------------
__global__ void __launch_bounds__(256) k_band(
    const float* __restrict__ P, const float* __restrict__ thr,
    u32* __restrict__ C_in, u32* __restrict__ bandCnt, u32* __restrict__ bandIdx,
    u32* __restrict__ bgt) {
    __shared__ u32 lidx[2048];
    __shared__ u32 lcnt, lhi, gbase;
    const int b = blockIdx.y, blk = blockIdx.x, t = threadIdx.x;
    if (t == 0) { lcnt = 0u; lhi = 0u; }
    __syncthreads();
    const float Tlo = thr[b], Thi = thr[8 + b];
    const int fi0 = blk * 1024 + t * 4;
    const float4 v = *(const float4*)&P[b * NNv + fi0];
    const float vv[4] = {v.x, v.y, v.z, v.w};
    u32 hc = 0;
#pragma unroll
    for (int q = 0; q < 4; ++q) {
        const float xq = vv[q];
        if (xq > Thi) ++hc;
        else if (xq >= Tlo) {
            const u32 p = atomicAdd(&lcnt, 1u);
            if (p < 2048u) lidx[p] = (u32)(fi0 + q);
        }
    }
    if (hc) atomicAdd(&lhi, hc);
    __syncthreads();
    if (t == 0) {
        bgt[b * 256 + blk] = lhi;
        if (lhi) atomicAdd(&C_in[b], lhi);
        gbase = lcnt ? atomicAdd(&bandCnt[b], lcnt) : 0u;
    }
    __syncthreads();
    const u32 ln = min(lcnt, 2048u);
    for (u32 p = t; p < ln; p += 256) {
        const u32 g = gbase + p;
        if (g < (u32)CAPB) bandIdx[b * CAPB + g] = lidx[p];
    }
}

// ---------------- exact recompute of band pairs (bit-identical to R1) -------
__device__ __forceinline__ float exact_p(const float* __restrict__ rai,
                                         const float* __restrict__ raj,
                                         const float* __restrict__ s_w2,
                                         const float* __restrict__ s_b1,
                                         const float* __restrict__ s_b2,
                                         const float* __restrict__ s_w3,
                                         float b3v) {
    float acc[32];
#pragma unroll
    for (int k = 0; k < 32; ++k) acc[k] = 0.f;
#pragma unroll 1
    for (int h0 = 0; h0 < 64; h0 += 16) {
        float A[16], J[16];
#pragma unroll
        for (int q = 0; q < 4; ++q) {
            *(float4*)&A[q * 4] = *(const float4*)&rai[h0 + q * 4];
            *(float4*)&J[q * 4] = *(const float4*)&raj[h0 + q * 4];
        }
#pragma unroll
        for (int hh = 0; hh < 16; ++hh) {
            const float tv = fmaxf((A[hh] + J[hh]) + s_b1[h0 + hh], 0.f);
#pragma unroll
            for (int k = 0; k < 32; ++k) acc[k] = fmaf(tv, s_w2[(h0 + hh) * 32 + k], acc[k]);
        }
    }
    float d = 0.f;
#pragma unroll
    for (int k = 0; k < 32; ++k) d = fmaf(fmaxf(acc[k] + s_b2[k], 0.f), s_w3[k], d);
    return 1.f / (1.f + expf(-(d + b3v)));
}

// exact recompute + fused band-select/scan tail (last block per batch)
__global__ void __launch_bounds__(256) k_band_exact(
    const float* __restrict__ ai, const float* __restrict__ aj,
    const float* __restrict__ b1, const float* __restrict__ w2,
    const float* __restrict__ b2, const float* __restrict__ w3,
    const float* __restrict__ b3, const u32* __restrict__ bandCnt,
    const u32* __restrict__ bandIdx, float* __restrict__ bandVal,
    u32* __restrict__ done3, const u32* __restrict__ C_in,
    u32* __restrict__ bitmap, const u32* __restrict__ bgt,
    u32* __restrict__ goff) {
    __shared__ float s_w2[2048];
    __shared__ float s_b1[64], s_b2[32], s_w3[32];
    __shared__ u32 red[256];
    __shared__ u32 lsel[256];
    __shared__ u32 tie[8192];
    __shared__ u32 tieCnt;
    __shared__ u32 amLast;
    const int b = blockIdx.y, t = threadIdx.x;
    {
        const int o = t * 8;
        *(float4*)&s_w2[o]     = *(const float4*)&w2[o];
        *(float4*)&s_w2[o + 4] = *(const float4*)&w2[o + 4];
        if (t < 64) s_b1[t] = b1[t];
        if (t < 32) { s_b2[t] = b2[t]; s_w3[t] = w3[t]; }
    }
    __syncthreads();
    const u32 nb = min(bandCnt[b], (u32)CAPB);
    const u32 e = blockIdx.x * 256 + t;
    if (e < nb) {
        const u32 idx = bandIdx[b * CAPB + e];
        const int i = (int)(idx >> 9), j = (int)(idx & 511u);
        const float b3v = b3[0];
        const float* ri  = &ai[(((b << 9) + i)) << 6];
        const float* rj  = &aj[(((b << 9) + j)) << 6];
        const float* rj2 = &ai[(((b << 9) + j)) << 6];
        const float* ri2 = &aj[(((b << 9) + i)) << 6];
        const float p1 = exact_p(ri, rj, s_w2, s_b1, s_b2, s_w3, b3v);   // P[i][j]
        const float p2 = exact_p(rj2, ri2, s_w2, s_b1, s_b2, s_w3, b3v); // P[j][i]
        bandVal[b * CAPB + e] = 0.5f * (p1 + p2);
    }
    // -------- last-block tail: band select + fused scan --------
    __threadfence();
    __syncthreads();
    if (t == 0) amLast = (atomicAdd(&done3[b], 1u) == 127u) ? 1u : 0u;
    __syncthreads();
    if (!amLast) return;
    __threadfence();
    const u32 Kp = (u32)KSEL - C_in[b];
    const u32* vb = (const u32*)(bandVal + b * CAPB);
    const u32* ib = bandIdx + b * CAPB;
    u32* bm = bitmap + b * 8192;
    lsel[t] = 0u;
    u32 mn = 0xFFFFFFFFu, mx = 0u;
    for (u32 k = t; k < nb; k += 256) { const u32 v = vb[k]; mn = min(mn, v); mx = max(mx, v); }
    red[t] = mn; __syncthreads();
    for (int s = 128; s > 0; s >>= 1) { if (t < s) red[t] = min(red[t], red[t + s]); __syncthreads(); }
    const u32 glo = red[0]; __syncthreads();
    red[t] = mx; __syncthreads();
    for (int s = 128; s > 0; s >>= 1) { if (t < s) red[t] = max(red[t], red[t + s]); __syncthreads(); }
    const u32 ghi = red[0]; __syncthreads();
    u32 lo = glo, hi = ghi;
    while (lo < hi) {
        const u32 mid = lo + ((hi - lo) >> 1);
        u32 c = 0;
        for (u32 k = t; k < nb; k += 256) c += (vb[k] > mid);
        red[t] = c; __syncthreads();
        for (int s = 128; s > 0; s >>= 1) { if (t < s) red[t] += red[t + s]; __syncthreads(); }
        const u32 tot = red[0]; __syncthreads();
        if (tot >= Kp) lo = mid + 1; else hi = mid;
    }
    const u32 Tx = lo;
    if (t == 0) tieCnt = 0u;
    __syncthreads();
    u32 c = 0;
    for (u32 k = t; k < nb; k += 256) {
        const u32 v = vb[k];
        if (v > Tx) {
            ++c;
            const u32 idx = ib[k];
            atomicOr(&bm[idx >> 5], 1u << (idx & 31u));
            atomicAdd(&lsel[idx >> 10], 1u);
        } else if (v == Tx) {
            const u32 p = atomicAdd(&tieCnt, 1u);
            if (p < 8192u) tie[p] = ib[k];
        }
    }
    red[t] = c; __syncthreads();
    for (int s = 128; s > 0; s >>= 1) { if (t < s) red[t] += red[t + s]; __syncthreads(); }
    const u32 Ap = red[0]; __syncthreads();
    const u32 Rp = Kp - Ap;
    const u32 E = min(tieCnt, 8192u);
    for (u32 k = t; k < E; k += 256) {
        const u32 my = tie[k];
        u32 r = 0;
        for (u32 m = 0; m < E; ++m) r += (tie[m] < my);
        if (r < Rp) {
            atomicOr(&bm[my >> 5], 1u << (my & 31u));
            atomicAdd(&lsel[my >> 10], 1u);
        }
    }
    __syncthreads();
    // fused exclusive scan of (bgt + lsel) -> goff
    const u32 g = bgt[b * 256 + t] + lsel[t];
    red[t] = g;
    __syncthreads();
    for (int off = 1; off < 256; off <<= 1) {
        const u32 a = (t >= off) ? red[t - off] : 0u;
        __syncthreads();
        red[t] += a;
        __syncthreads();
    }
    goff[b * 256 + t] = red[t] - g;
}

// ---------------- write ------------------------------------------------------
__global__ void k_write(const float* __restrict__ P, const float* __restrict__ thr,
                        const u32* __restrict__ bitmap, const u32* __restrict__ goff,
                        float* __restrict__ out) {
    __shared__ u32 sg[256];
    const int b = blockIdx.y, blk = blockIdx.x, t = threadIdx.x;
    const float Thi = thr[8 + b];
    const int pbase = b * NNv;
    const int fi0 = blk * 1024 + t * 4;
    const float4 v = *(const float4*)&P[pbase + fi0];
    const float vv[4] = {v.x, v.y, v.z, v.w};
    const u32 w = bitmap[b * 8192 + (fi0 >> 5)];
    const u32 sh = (u32)(fi0 & 31);
    bool sel[4];
    u32 cnt = 0;
#pragma unroll
    for (int q = 0; q < 4; ++q) {
        sel[q] = (vv[q] > Thi) || ((w >> (sh + q)) & 1u);
        cnt += sel[q];
    }
    sg[t] = cnt;
    __syncthreads();
    for (int off = 1; off < 256; off <<= 1) {
        const u32 a = (t >= off) ? sg[t - off] : 0u;
        __syncthreads();
        sg[t] += a;
        __syncthreads();
    }
    u32 pos = goff[b * 256 + blk] + sg[t] - cnt;
#pragma unroll
    for (int q = 0; q < 4; ++q) {
        if (sel[q]) {
            if (pos < (u32)KSEL) {
                const int g = b * KSEL + (int)pos;
                const int fi = fi0 + q;
                const int row = fi >> 9, col = fi & 511;
                out[g]           = (float)(row + (b << 9));
                out[BKv + g]     = (float)(col + (b << 9));
                out[2 * BKv + g] = vv[q];
                out[3 * BKv + pbase + fi] = vv[q];
            }
            ++pos;
        }
    }
}

// ---------------------------------------------------------------------------
extern "C" void kernel_launch(void* const* d_in, const int* in_sizes, int n_in,
                              void* d_out, int out_size, void* d_ws, size_t ws_size,
                              hipStream_t stream) {
    const float* x      = (const float*)d_in[0];
    const float* w_emb  = (const float*)d_in[1];
    const float* b_emb  = (const float*)d_in[2];
    const float* w_proj = (const float*)d_in[3];
    const float* b_proj = (const float*)d_in[4];
    const float* w1     = (const float*)d_in[5];
    const float* b1     = (const float*)d_in[6];
    const float* w2     = (const float*)d_in[7];
    const float* b2     = (const float*)d_in[8];
    const float* w3     = (const float*)d_in[9];
    const float* b3     = (const float*)d_in[10];
    (void)in_sizes; (void)n_in; (void)ws_size;

    char* ws = (char*)d_ws;
    float* ai      = (float*)(ws);                    // 1 MiB
    float* aj      = (float*)(ws + 1048576);          // 1 MiB
    float* ai256   = (float*)(ws + 2097152);          // 1 MiB
    float* ajb256  = (float*)(ws + 3145728);          // 1 MiB
    float* probs   = (float*)(ws + 4194304);          // 8 MiB
    u32*   bandIdx = (u32*)  (ws + 12582912);         // 1 MiB
    float* bandVal = (float*)(ws + 13631488);         // 1 MiB
    const size_t SOFF = 14680064;
    u32*   hist8   = (u32*)  (ws + SOFF);             // 8 KiB   [zeroed]
    u32*   hist13  = (u32*)  (ws + SOFF + 8192);      // 256 KiB [zeroed]
    u32*   c8      = (u32*)  (ws + SOFF + 270336);
    u32*   rem1    = (u32*)  (ws + SOFF + 270368);
    float* thr     = (float*)(ws + SOFF + 270400);    // Tlo[8], Thi[8]
    u32*   C_in    = (u32*)  (ws + SOFF + 270464);
    u32*   bandCnt = (u32*)  (ws + SOFF + 270496);
    u32*   done1   = (u32*)  (ws + SOFF + 270528);
    u32*   done2   = (u32*)  (ws + SOFF + 270560);
    u32*   done3   = (u32*)  (ws + SOFF + 270592);
    u32*   bitmap  = (u32*)  (ws + SOFF + 270624);    // 256 KiB [zeroed]
    u32*   bgt     = (u32*)  (ws + SOFF + 532768);    // 8 KiB (fully written)
    u32*   goff    = (u32*)  (ws + SOFF + 540960);    // 8 KiB (fully written)

    float* out = (float*)d_out;

    hipMemsetAsync(d_out, 0, (size_t)out_size * sizeof(float), stream);
    hipMemsetAsync(ws + SOFF, 0, 532768, stream);     // hist8..bitmap + counters

    k_embed<<<1024, dim3(64, 4, 1), 0, stream>>>(x, w_emb, b_emb, w_proj, b_proj,
                                                 w1, b1, ai, aj, ai256, ajb256);
    k_pairs_sym<<<dim3(136, 8), 256, 0, stream>>>(ai256, ajb256, w2, b2, w3, b3,
                                                  probs, hist8, done1, c8, rem1);
    k_hist13<<<dim3(64, 8), 256, 0, stream>>>(probs, c8, hist13, done2, rem1, thr);
    k_band<<<dim3(256, 8), 256, 0, stream>>>(probs, thr, C_in, bandCnt, bandIdx, bgt);
    k_band_exact<<<dim3(128, 8), 256, 0, stream>>>(ai, aj, b1, w2, b2, w3, b3,
                                                   bandCnt, bandIdx, bandVal,
                                                   done3, C_in, bitmap, bgt, goff);
    k_write<<<dim3(256, 8), 256, 0, stream>>>(probs, thr, bitmap, goff, out);
}

// Round 9
// 198.455 us; speedup vs baseline: 1.8589x; 1.8589x over previous
//
#include <hip/hip_runtime.h>

#define NV 512
#define BV 8
#define KSEL 26163
#define NNv (NV*NV)          // 262144
#define BKv (BV*KSEL)        // 209304
#define CAPB 32768
#define DELTA 1e-4f          // approx-score error bound (worst-case ~2e-5)

typedef unsigned int u32;
typedef __attribute__((ext_vector_type(2))) float f32x2;
typedef __attribute__((ext_vector_type(4))) float f32x4;
typedef __attribute__((ext_vector_type(4))) u32 u32x4;
typedef __attribute__((ext_vector_type(8))) _Float16 f16x8;

__device__ __forceinline__ f32x2 pk_add(f32x2 a, f32x2 b) {
    f32x2 d; asm("v_pk_add_f32 %0, %1, %2" : "=v"(d) : "v"(a), "v"(b)); return d;
}
__device__ __forceinline__ f32x2 pk_fma(f32x2 a, f32x2 b, f32x2 c) {
    f32x2 d; asm("v_pk_fma_f32 %0, %1, %2, %3" : "=v"(d) : "v"(a), "v"(b), "v"(c)); return d;
}
__device__ __forceinline__ u32 pkrtz(float a, float b) {
    u32 d; asm("v_cvt_pkrtz_f16_f32 %0, %1, %2" : "=v"(d) : "v"(a), "v"(b)); return d;
}
__device__ __forceinline__ float fast_sigmoid(float z) {
    float e, p;
    asm("v_exp_f32 %0, %1" : "=v"(e) : "v"(-z * 1.44269504f));
    asm("v_rcp_f32 %0, %1" : "=v"(p) : "v"(1.f + e));
    return p;
}

// ---------------- embed: x -> emb -> ai, aj (exact) + ai256, ajb256 ---------
__global__ void __launch_bounds__(256) k_embed(
    const float* __restrict__ x, const float* __restrict__ w_emb,
    const float* __restrict__ b_emb, const float* __restrict__ w_proj,
    const float* __restrict__ b_proj, const float* __restrict__ w1,
    const float* __restrict__ b1,
    float* __restrict__ ai, float* __restrict__ aj,
    float* __restrict__ ai256, float* __restrict__ ajb256) {
    __shared__ float sh[4][64];
    __shared__ float se[4][64];
    const int c = threadIdx.x;        // 0..63
    const int lr = threadIdx.y;       // 0..3
    const int row = blockIdx.x * 4 + lr;
    const float xv = x[row];
    sh[lr][c] = fmaxf(fmaf(xv, w_emb[c], b_emb[c]), 0.f);
    __syncthreads();
    float e = 0.f;
#pragma unroll
    for (int h = 0; h < 64; ++h) e = fmaf(sh[lr][h], w_proj[h * 64 + c], e);
    se[lr][c] = e + b_proj[c];
    __syncthreads();
    float a0 = 0.f, a1 = 0.f;
#pragma unroll
    for (int h = 0; h < 64; ++h) {
        const float ev = se[lr][h];
        a0 = fmaf(ev, w1[h * 64 + c], a0);
        a1 = fmaf(ev, w1[(64 + h) * 64 + c], a1);
    }
    ai[row * 64 + c] = a0;
    aj[row * 64 + c] = a1;
    ai256[row * 64 + c] = a0 * 256.0f;                 // exact (pow2)
    ajb256[row * 64 + c] = (a1 + b1[c]) * 256.0f;
}

// ---------------- fused pair scorer + symmetrize + hist8 --------------------
__global__ void __launch_bounds__(256) k_pairs_sym(
    const float* __restrict__ ai256, const float* __restrict__ ajb256,
    const float* __restrict__ w2, const float* __restrict__ b2,
    const float* __restrict__ w3, const float* __restrict__ b3,
    float* __restrict__ probs, u32* __restrict__ hist8) {
    __shared__ float sI[2048];        // ai256 rows I0 (32 x 64)
    __shared__ float sJ[2048];        // ai256 rows J0
    __shared__ float sp1[32 * 33];    // sigma(s(i,j)) at [ii][jj], stride 33
    __shared__ float sp2[32 * 33];    // sigma(s(j,i)) at [ii][jj]
    __shared__ u32 lh[1024];          // 4-replica 256-bin hist
    const int tid = threadIdx.x;
    const int b = blockIdx.y;
    int remb = blockIdx.x, ta = 0;
    while (remb >= 16 - ta) { remb -= 16 - ta; ++ta; }
    const int tb = ta + remb;         // ta <= tb
    const int i0 = ta << 5, j0 = tb << 5;
    {
        const int r = tid >> 3, c8v = (tid & 7) << 3;
        const float* srcI = &ai256[(((b << 9) + i0 + r) << 6) + c8v];
        *(float4*)&sI[(r << 6) + c8v]     = *(const float4*)&srcI[0];
        *(float4*)&sI[(r << 6) + c8v + 4] = *(const float4*)&srcI[4];
        const float* srcJ = &ai256[(((b << 9) + j0 + r) << 6) + c8v];
        *(float4*)&sJ[(r << 6) + c8v]     = *(const float4*)&srcJ[0];
        *(float4*)&sJ[(r << 6) + c8v + 4] = *(const float4*)&srcJ[4];
        lh[tid] = 0; lh[256 + tid] = 0; lh[512 + tid] = 0; lh[768 + tid] = 0;
    }
    const int lane = tid & 63;
    const int lp = lane & 15, lg = lane >> 4;
    const int wave = tid >> 6;
    const int dir = wave >> 1, wc = wave & 1;
    const int colb = (wc << 4) + lp;                 // 0..31 within tile
    const int colg = (dir ? i0 : j0) + colb;         // global col row-index

    alignas(16) float ajr[2][8];
    {
        const float* base = &ajb256[(((b << 9) + colg) << 6) + (lg << 3)];
        *(float4*)&ajr[0][0] = *(const float4*)&base[0];
        *(float4*)&ajr[0][4] = *(const float4*)&base[4];
        *(float4*)&ajr[1][0] = *(const float4*)&base[32];
        *(float4*)&ajr[1][4] = *(const float4*)&base[36];
    }
    f16x8 Ah[2][2], Al[2][2];         // w2^T hi / lo*2048 [ktile][hchunk]
#pragma unroll
    for (int kt = 0; kt < 2; ++kt)
#pragma unroll
        for (int ch = 0; ch < 2; ++ch)
#pragma unroll
            for (int e = 0; e < 8; ++e) {
                const float wv2 = w2[((ch << 5) + (lg << 3) + e) * 32 + (kt << 4) + lp];
                const _Float16 wh = (_Float16)wv2;
                Ah[kt][ch][e] = wh;
                Al[kt][ch][e] = (_Float16)((wv2 - (float)wh) * 2048.0f);
            }
    float b2f[2][4], w3f[2][4];
#pragma unroll
    for (int kt = 0; kt < 2; ++kt)
#pragma unroll
        for (int r = 0; r < 4; ++r) {
            b2f[kt][r] = b2[(kt << 4) + (lg << 2) + r] * 256.0f;
            w3f[kt][r] = w3[(kt << 4) + (lg << 2) + r] * 0.00390625f;
        }
    const float b3v = b3[0];
    __syncthreads();

    const float* __restrict__ sA = dir ? sJ : sI;
    float* __restrict__ spO = dir ? sp2 : sp1;
    const f32x2 CN1 = {-1.f, -1.f};

    for (int r = 0; r < 32; ++r) {
        alignas(16) float ar[2][8];
        *(float4*)&ar[0][0] = *(const float4*)&sA[(r << 6) + (lg << 3)];
        *(float4*)&ar[0][4] = *(const float4*)&sA[(r << 6) + (lg << 3) + 4];
        *(float4*)&ar[1][0] = *(const float4*)&sA[(r << 6) + 32 + (lg << 3)];
        *(float4*)&ar[1][4] = *(const float4*)&sA[(r << 6) + 32 + (lg << 3) + 4];
        alignas(16) u32 hw[2][4], lw[2][4];
#pragma unroll
        for (int c = 0; c < 2; ++c)
#pragma unroll
            for (int e2 = 0; e2 < 4; ++e2) {
                const f32x2 a2 = *(const f32x2*)&ar[c][e2 * 2];
                const f32x2 j2 = *(const f32x2*)&ajr[c][e2 * 2];
                f32x2 u2 = pk_add(a2, j2);
                u2[0] = fmaxf(u2[0], 0.f);
                u2[1] = fmaxf(u2[1], 0.f);
                hw[c][e2] = pkrtz(u2[0], u2[1]);
                f32x2 hif;
                hif[0] = __uint_as_float(__float_as_uint(u2[0]) & 0xFFFFE000u);
                hif[1] = __uint_as_float(__float_as_uint(u2[1]) & 0xFFFFE000u);
                const f32x2 lo = pk_fma(hif, CN1, u2);   // exact residual
                lw[c][e2] = pkrtz(lo[0], lo[1]);
            }
        const f16x8 Bh0 = __builtin_bit_cast(f16x8, *(u32x4*)&hw[0][0]);
        const f16x8 Bh1 = __builtin_bit_cast(f16x8, *(u32x4*)&hw[1][0]);
        const f16x8 Bl0 = __builtin_bit_cast(f16x8, *(u32x4*)&lw[0][0]);
        const f16x8 Bl1 = __builtin_bit_cast(f16x8, *(u32x4*)&lw[1][0]);
        // main acc (scale 2^8): wh*th + wh*tl ; c acc (scale 2^19): wl*th
        f32x4 am0 = {0.f,0.f,0.f,0.f}, am1 = {0.f,0.f,0.f,0.f};
        f32x4 ac0 = {0.f,0.f,0.f,0.f}, ac1 = {0.f,0.f,0.f,0.f};
        am0 = __builtin_amdgcn_mfma_f32_16x16x32_f16(Ah[0][0], Bh0, am0, 0, 0, 0);
        am0 = __builtin_amdgcn_mfma_f32_16x16x32_f16(Ah[0][1], Bh1, am0, 0, 0, 0);
        am0 = __builtin_amdgcn_mfma_f32_16x16x32_f16(Ah[0][0], Bl0, am0, 0, 0, 0);
        am0 = __builtin_amdgcn_mfma_f32_16x16x32_f16(Ah[0][1], Bl1, am0, 0, 0, 0);
        ac0 = __builtin_amdgcn_mfma_f32_16x16x32_f16(Al[0][0], Bh0, ac0, 0, 0, 0);
        ac0 = __builtin_amdgcn_mfma_f32_16x16x32_f16(Al[0][1], Bh1, ac0, 0, 0, 0);
        am1 = __builtin_amdgcn_mfma_f32_16x16x32_f16(Ah[1][0], Bh0, am1, 0, 0, 0);
        am1 = __builtin_amdgcn_mfma_f32_16x16x32_f16(Ah[1][1], Bh1, am1, 0, 0, 0);
        am1 = __builtin_amdgcn_mfma_f32_16x16x32_f16(Ah[1][0], Bl0, am1, 0, 0, 0);
        am1 = __builtin_amdgcn_mfma_f32_16x16x32_f16(Ah[1][1], Bl1, am1, 0, 0, 0);
        ac1 = __builtin_amdgcn_mfma_f32_16x16x32_f16(Al[1][0], Bh0, ac1, 0, 0, 0);
        ac1 = __builtin_amdgcn_mfma_f32_16x16x32_f16(Al[1][1], Bh1, ac1, 0, 0, 0);
        float s = 0.f;
#pragma unroll
        for (int q = 0; q < 4; ++q) {
            const float amc = fmaf(ac0[q], 4.8828125e-4f, am0[q]);   // + c*2^-11
            s = fmaf(fmaxf(amc + b2f[0][q], 0.f), w3f[0][q], s);
        }
#pragma unroll
        for (int q = 0; q < 4; ++q) {
            const float amc = fmaf(ac1[q], 4.8828125e-4f, am1[q]);
            s = fmaf(fmaxf(amc + b2f[1][q], 0.f), w3f[1][q], s);
        }
        s += __shfl_xor(s, 16);
        s += __shfl_xor(s, 32);
        const float p = fast_sigmoid(s + b3v);
        if (lane < 16) {
            if (dir == 0) spO[r * 33 + colb] = p;     // sigma(s(i0+r, j0+colb))
            else          spO[colb * 33 + r] = p;     // sigma(s(j0+r, i0+colb))
        }
    }
    __syncthreads();

    // average, diag-zero, write both tiles, histogram
    {
        const int pr = tid >> 3;              // ii
        const int pc = (tid & 7) << 2;        // jj0
        const int rep = (tid & 3) << 8;
        const bool diag = (ta == tb);
        float4 vo;
        float vq[4];
#pragma unroll
        for (int q = 0; q < 4; ++q) {
            float v = 0.5f * (sp1[pr * 33 + pc + q] + sp2[pr * 33 + pc + q]);
            if (diag && pr == pc + q) v = 0.f;
            vq[q] = v;
            atomicAdd(&lh[rep + (__float_as_uint(v) >> 24)], diag ? 1u : 2u);
        }
        vo.x = vq[0]; vo.y = vq[1]; vo.z = vq[2]; vo.w = vq[3];
        *(float4*)&probs[(((b << 9) + i0 + pr) << 9) + j0 + pc] = vo;
        if (!diag) {
            float4 w4;
            w4.x = 0.5f * (sp1[(pc + 0) * 33 + pr] + sp2[(pc + 0) * 33 + pr]);
            w4.y = 0.5f * (sp1[(pc + 1) * 33 + pr] + sp2[(pc + 1) * 33 + pr]);
            w4.z = 0.5f * (sp1[(pc + 2) * 33 + pr] + sp2[(pc + 2) * 33 + pr]);
            w4.w = 0.5f * (sp1[(pc + 3) * 33 + pr] + sp2[(pc + 3) * 33 + pr]);
            *(float4*)&probs[(((b << 9) + j0 + pr) << 9) + i0 + pc] = w4;
        }
    }
    __syncthreads();
    const u32 sum = lh[tid] + lh[256 + tid] + lh[512 + tid] + lh[768 + tid];
    if (sum) atomicAdd(&hist8[b * 256 + tid], sum);
}

// ---------------- 13-bit filtered LDS histogram (derives c8 in-block) -------
__global__ void __launch_bounds__(256) k_hist13(
    const float* __restrict__ probs, const u32* __restrict__ hist8,
    u32* __restrict__ hist13) {
    __shared__ u32 lh[8192];
    __shared__ u32 s8[256];
    __shared__ u32 selsh;
    const int t = threadIdx.x;
    const int b = blockIdx.y;
    for (int k = t; k < 8192; k += 256) lh[k] = 0u;
    s8[t] = hist8[b * 256 + t];
    __syncthreads();
    for (int off = 1; off < 256; off <<= 1) {   // inclusive suffix sums
        const u32 v = (t + off < 256) ? s8[t + off] : 0u;
        __syncthreads();
        s8[t] += v;
        __syncthreads();
    }
    {
        const u32 above = (t < 255) ? s8[t + 1] : 0u;
        if (s8[t] >= (u32)KSEL && above < (u32)KSEL) selsh = (u32)t;
    }
    __syncthreads();
    const u32 sel = selsh;
    const float* Pb = probs + b * NNv;
    const int base = blockIdx.x * 4096 + t;
#pragma unroll
    for (int e = 0; e < 16; ++e) {
        const u32 key = __float_as_uint(Pb[base + e * 256]);
        if ((key >> 24) == sel) atomicAdd(&lh[(key >> 11) & 8191u], 1u);
    }
    __syncthreads();
    for (int k = t; k < 8192; k += 256) {
        const u32 v = lh[k];
        if (v) atomicAdd(&hist13[b * 8192 + k], v);
    }
}

// ---------------- 13-bit select -> Tlo/Thi (derives c8+rem in-block) --------
__global__ void __launch_bounds__(256) k_sel13(
    const u32* __restrict__ hist8, const u32* __restrict__ hist13,
    float* __restrict__ thr) {
    __shared__ u32 s8[256];
    __shared__ u32 s[256];
    __shared__ u32 c8sh, remsh;
    const int b = blockIdx.x, t = threadIdx.x;
    s8[t] = hist8[b * 256 + t];
    __syncthreads();
    for (int off = 1; off < 256; off <<= 1) {
        const u32 v = (t + off < 256) ? s8[t + off] : 0u;
        __syncthreads();
        s8[t] += v;
        __syncthreads();
    }
    {
        const u32 above = (t < 255) ? s8[t + 1] : 0u;
        if (s8[t] >= (u32)KSEL && above < (u32)KSEL) {
            c8sh = (u32)t;
            remsh = (u32)KSEL - above;
        }
    }
    __syncthreads();
    const u32 c8 = c8sh, remv = remsh;
    const u32* H = hist13 + b * 8192;
    u32 sum = 0;
    for (int k = 0; k < 32; ++k) sum += H[t * 32 + k];
    s[t] = sum;
    __syncthreads();
    for (int off = 1; off < 256; off <<= 1) {   // inclusive suffix sums
        const u32 v = (t + off < 256) ? s[t + off] : 0u;
        __syncthreads();
        s[t] += v;
        __syncthreads();
    }
    const u32 above = (t < 255) ? s[t + 1] : 0u;
    if (s[t] >= remv && above < remv) {
        u32 cum = above;
        int c = 31;
        for (; c >= 0; --c) {
            cum += H[t * 32 + c];
            if (cum >= remv) break;
        }
        const u32 p21 = (c8 << 13) | (u32)(t * 32 + c);
        thr[b]     = __uint_as_float(p21 << 11) - 2.f * DELTA;        // Tlo
        thr[8 + b] = __uint_as_float((p21 + 1u) << 11) + 2.f * DELTA; // Thi
    }
}

// ---------------- exact scorer (bit-identical to R1 arithmetic) -------------
__device__ __forceinline__ float exact_p(const float* __restrict__ rai,
                                         const float* __restrict__ raj,
                                         const float* __restrict__ s_w2,
                                         const float* __restrict__ s_b1,
                                         const float* __restrict__ s_b2,
                                         const float* __restrict__ s_w3,
                                         float b3v) {
    float acc[32];
#pragma unroll
    for (int k = 0; k < 32; ++k) acc[k] = 0.f;
#pragma unroll 1
    for (int h0 = 0; h0 < 64; h0 += 16) {
        float A[16], J[16];
#pragma unroll
        for (int q = 0; q < 4; ++q) {
            *(float4*)&A[q * 4] = *(const float4*)&rai[h0 + q * 4];
            *(float4*)&J[q * 4] = *(const float4*)&raj[h0 + q * 4];
        }
#pragma unroll
        for (int hh = 0; hh < 16; ++hh) {
            const float tv = fmaxf((A[hh] + J[hh]) + s_b1[h0 + hh], 0.f);
#pragma unroll
            for (int k = 0; k < 32; ++k) acc[k] = fmaf(tv, s_w2[(h0 + hh) * 32 + k], acc[k]);
        }
    }
    float d = 0.f;
#pragma unroll
    for (int k = 0; k < 32; ++k) d = fmaf(fmaxf(acc[k] + s_b2[k], 0.f), s_w3[k], d);
    return 1.f / (1.f + expf(-(d + b3v)));
}

// ---------------- band collect + in-block exact recompute -------------------
__global__ void __launch_bounds__(256) k_band(
    const float* __restrict__ P, const float* __restrict__ thr,
    const float* __restrict__ ai, const float* __restrict__ aj,
    const float* __restrict__ b1, const float* __restrict__ w2,
    const float* __restrict__ b2, const float* __restrict__ w3,
    const float* __restrict__ b3,
    u32* __restrict__ C_in, u32* __restrict__ bandCnt,
    u32* __restrict__ bandIdx, float* __restrict__ bandVal,
    u32* __restrict__ bgt) {
    __shared__ float s_w2[2048];
    __shared__ float s_b1[64], s_b2[32], s_w3[32];
    __shared__ u32 lidx[2048];
    __shared__ u32 lcnt, lhi, gbase;
    const int b = blockIdx.y, blk = blockIdx.x, t = threadIdx.x;
    {
        const int o = t * 8;
        *(float4*)&s_w2[o]     = *(const float4*)&w2[o];
        *(float4*)&s_w2[o + 4] = *(const float4*)&w2[o + 4];
        if (t < 64) s_b1[t] = b1[t];
        if (t < 32) { s_b2[t] = b2[t]; s_w3[t] = w3[t]; }
        if (t == 0) { lcnt = 0u; lhi = 0u; }
    }
    __syncthreads();
    const float Tlo = thr[b], Thi = thr[8 + b];
    const int fi0 = blk * 1024 + t * 4;
    const float4 v = *(const float4*)&P[b * NNv + fi0];
    const float vv[4] = {v.x, v.y, v.z, v.w};
    u32 hc = 0;
#pragma unroll
    for (int q = 0; q < 4; ++q) {
        const float xq = vv[q];
        if (xq > Thi) ++hc;
        else if (xq >= Tlo) {
            const u32 p = atomicAdd(&lcnt, 1u);
            if (p < 2048u) lidx[p] = (u32)(fi0 + q);
        }
    }
    if (hc) atomicAdd(&lhi, hc);
    __syncthreads();
    if (t == 0) {
        bgt[b * 256 + blk] = lhi;
        if (lhi) atomicAdd(&C_in[b], lhi);
        gbase = lcnt ? atomicAdd(&bandCnt[b], lcnt) : 0u;
    }
    __syncthreads();
    const u32 ln = min(lcnt, 2048u);
    const float b3v = b3[0];
    for (u32 p = t; p < ln; p += 256) {
        const u32 g = gbase + p;
        if (g < (u32)CAPB) {
            const u32 idx = lidx[p];
            const int i = (int)(idx >> 9), j = (int)(idx & 511u);
            const float* ri  = &ai[(((b << 9) + i)) << 6];
            const float* rj  = &aj[(((b << 9) + j)) << 6];
            const float* rj2 = &ai[(((b << 9) + j)) << 6];
            const float* ri2 = &aj[(((b << 9) + i)) << 6];
            const float p1 = exact_p(ri, rj, s_w2, s_b1, s_b2, s_w3, b3v);   // P[i][j]
            const float p2 = exact_p(rj2, ri2, s_w2, s_b1, s_b2, s_w3, b3v); // P[j][i]
            bandIdx[b * CAPB + g] = idx;
            bandVal[b * CAPB + g] = 0.5f * (p1 + p2);
        }
    }
}

// ---------------- band select + fused per-block counts + scan ---------------
__global__ void __launch_bounds__(256) k_band_select(
    const u32* __restrict__ bandCnt, const u32* __restrict__ C_in,
    const u32* __restrict__ bandIdx, const float* __restrict__ bandVal,
    u32* __restrict__ bitmap, const u32* __restrict__ bgt,
    u32* __restrict__ goff) {
    __shared__ u32 red[256];
    __shared__ u32 lsel[256];
    __shared__ u32 tie[8192];
    __shared__ u32 tieCnt;
    const int b = blockIdx.x, t = threadIdx.x;
    const u32 nb = min(bandCnt[b], (u32)CAPB);
    const u32 Kp = (u32)KSEL - C_in[b];
    const u32* vb = (const u32*)(bandVal + b * CAPB);
    const u32* ib = bandIdx + b * CAPB;
    u32* bm = bitmap + b * 8192;
    lsel[t] = 0u;
    u32 mn = 0xFFFFFFFFu, mx = 0u;
    for (u32 k = t; k < nb; k += 256) { const u32 v = vb[k]; mn = min(mn, v); mx = max(mx, v); }
    red[t] = mn; __syncthreads();
    for (int s = 128; s > 0; s >>= 1) { if (t < s) red[t] = min(red[t], red[t + s]); __syncthreads(); }
    const u32 glo = red[0]; __syncthreads();
    red[t] = mx; __syncthreads();
    for (int s = 128; s > 0; s >>= 1) { if (t < s) red[t] = max(red[t], red[t + s]); __syncthreads(); }
    const u32 ghi = red[0]; __syncthreads();
    u32 lo = glo, hi = ghi;
    while (lo < hi) {
        const u32 mid = lo + ((hi - lo) >> 1);
        u32 c = 0;
        for (u32 k = t; k < nb; k += 256) c += (vb[k] > mid);
        red[t] = c; __syncthreads();
        for (int s = 128; s > 0; s >>= 1) { if (t < s) red[t] += red[t + s]; __syncthreads(); }
        const u32 tot = red[0]; __syncthreads();
        if (tot >= Kp) lo = mid + 1; else hi = mid;
    }
    const u32 Tx = lo;
    if (t == 0) tieCnt = 0u;
    __syncthreads();
    u32 c = 0;
    for (u32 k = t; k < nb; k += 256) {
        const u32 v = vb[k];
        if (v > Tx) {
            ++c;
            const u32 idx = ib[k];
            atomicOr(&bm[idx >> 5], 1u << (idx & 31u));
            atomicAdd(&lsel[idx >> 10], 1u);
        } else if (v == Tx) {
            const u32 p = atomicAdd(&tieCnt, 1u);
            if (p < 8192u) tie[p] = ib[k];
        }
    }
    red[t] = c; __syncthreads();
    for (int s = 128; s > 0; s >>= 1) { if (t < s) red[t] += red[t + s]; __syncthreads(); }
    const u32 Ap = red[0]; __syncthreads();
    const u32 Rp = Kp - Ap;
    const u32 E = min(tieCnt, 8192u);
    for (u32 k = t; k < E; k += 256) {
        const u32 my = tie[k];
        u32 r = 0;
        for (u32 m = 0; m < E; ++m) r += (tie[m] < my);
        if (r < Rp) {
            atomicOr(&bm[my >> 5], 1u << (my & 31u));
            atomicAdd(&lsel[my >> 10], 1u);
        }
    }
    __syncthreads();
    // fused exclusive scan of (bgt + lsel) -> goff
    const u32 g = bgt[b * 256 + t] + lsel[t];
    red[t] = g;
    __syncthreads();
    for (int off = 1; off < 256; off <<= 1) {
        const u32 a = (t >= off) ? red[t - off] : 0u;
        __syncthreads();
        red[t] += a;
        __syncthreads();
    }
    goff[b * 256 + t] = red[t] - g;
}

// ---------------- write ------------------------------------------------------
__global__ void k_write(const float* __restrict__ P, const float* __restrict__ thr,
                        const u32* __restrict__ bitmap, const u32* __restrict__ goff,
                        float* __restrict__ out) {
    __shared__ u32 sg[256];
    const int b = blockIdx.y, blk = blockIdx.x, t = threadIdx.x;
    const float Thi = thr[8 + b];
    const int pbase = b * NNv;
    const int fi0 = blk * 1024 + t * 4;
    const float4 v = *(const float4*)&P[pbase + fi0];
    const float vv[4] = {v.x, v.y, v.z, v.w};
    const u32 w = bitmap[b * 8192 + (fi0 >> 5)];
    const u32 sh = (u32)(fi0 & 31);
    bool sel[4];
    u32 cnt = 0;
#pragma unroll
    for (int q = 0; q < 4; ++q) {
        sel[q] = (vv[q] > Thi) || ((w >> (sh + q)) & 1u);
        cnt += sel[q];
    }
    sg[t] = cnt;
    __syncthreads();
    for (int off = 1; off < 256; off <<= 1) {
        const u32 a = (t >= off) ? sg[t - off] : 0u;
        __syncthreads();
        sg[t] += a;
        __syncthreads();
    }
    u32 pos = goff[b * 256 + blk] + sg[t] - cnt;
#pragma unroll
    for (int q = 0; q < 4; ++q) {
        if (sel[q]) {
            if (pos < (u32)KSEL) {
                const int g = b * KSEL + (int)pos;
                const int fi = fi0 + q;
                const int row = fi >> 9, col = fi & 511;
                out[g]           = (float)(row + (b << 9));
                out[BKv + g]     = (float)(col + (b << 9));
                out[2 * BKv + g] = vv[q];
                out[3 * BKv + pbase + fi] = vv[q];
            }
            ++pos;
        }
    }
}

// ---------------------------------------------------------------------------
extern "C" void kernel_launch(void* const* d_in, const int* in_sizes, int n_in,
                              void* d_out, int out_size, void* d_ws, size_t ws_size,
                              hipStream_t stream) {
    const float* x      = (const float*)d_in[0];
    const float* w_emb  = (const float*)d_in[1];
    const float* b_emb  = (const float*)d_in[2];
    const float* w_proj = (const float*)d_in[3];
    const float* b_proj = (const float*)d_in[4];
    const float* w1     = (const float*)d_in[5];
    const float* b1     = (const float*)d_in[6];
    const float* w2     = (const float*)d_in[7];
    const float* b2     = (const float*)d_in[8];
    const float* w3     = (const float*)d_in[9];
    const float* b3     = (const float*)d_in[10];
    (void)in_sizes; (void)n_in; (void)ws_size;

    char* ws = (char*)d_ws;
    float* ai      = (float*)(ws);                    // 1 MiB
    float* aj      = (float*)(ws + 1048576);          // 1 MiB
    float* ai256   = (float*)(ws + 2097152);          // 1 MiB
    float* ajb256  = (float*)(ws + 3145728);          // 1 MiB
    float* probs   = (float*)(ws + 4194304);          // 8 MiB
    u32*   bandIdx = (u32*)  (ws + 12582912);         // 1 MiB
    float* bandVal = (float*)(ws + 13631488);         // 1 MiB
    const size_t SOFF = 14680064;
    u32*   hist8   = (u32*)  (ws + SOFF);             // 8 KiB   [zeroed]
    u32*   hist13  = (u32*)  (ws + SOFF + 8192);      // 256 KiB [zeroed]
    float* thr     = (float*)(ws + SOFF + 270336);    // 64 B
    u32*   C_in    = (u32*)  (ws + SOFF + 270400);    //          [zeroed]
    u32*   bandCnt = (u32*)  (ws + SOFF + 270432);    //          [zeroed]
    u32*   bitmap  = (u32*)  (ws + SOFF + 270464);    // 256 KiB [zeroed]
    u32*   bgt     = (u32*)  (ws + SOFF + 532608);    // 8 KiB (fully written)
    u32*   goff    = (u32*)  (ws + SOFF + 540800);    // 8 KiB (fully written)

    float* out = (float*)d_out;

    hipMemsetAsync(d_out, 0, (size_t)out_size * sizeof(float), stream);
    hipMemsetAsync(ws + SOFF, 0, 532608, stream);     // hist8..bitmap

    k_embed<<<1024, dim3(64, 4, 1), 0, stream>>>(x, w_emb, b_emb, w_proj, b_proj,
                                                 w1, b1, ai, aj, ai256, ajb256);
    k_pairs_sym<<<dim3(136, 8), 256, 0, stream>>>(ai256, ajb256, w2, b2, w3, b3,
                                                  probs, hist8);
    k_hist13<<<dim3(64, 8), 256, 0, stream>>>(probs, hist8, hist13);
    k_sel13<<<8, 256, 0, stream>>>(hist8, hist13, thr);
    k_band<<<dim3(256, 8), 256, 0, stream>>>(probs, thr, ai, aj, b1, w2, b2, w3, b3,
                                             C_in, bandCnt, bandIdx, bandVal, bgt);
    k_band_select<<<8, 256, 0, stream>>>(bandCnt, C_in, bandIdx, bandVal,
                                         bitmap, bgt, goff);
    k_write<<<dim3(256, 8), 256, 0, stream>>>(probs, thr, bitmap, goff, out);
}

// Round 10
// 196.156 us; speedup vs baseline: 1.8807x; 1.0117x over previous
//
#include <hip/hip_runtime.h>

#define NV 512
#define BV 8
#define KSEL 26163
#define NNv (NV*NV)          // 262144
#define BKv (BV*KSEL)        // 209304
#define CAPB 32768
#define DELTA 1e-4f          // approx-score error bound (worst-case ~2e-5)

typedef unsigned int u32;
typedef __attribute__((ext_vector_type(2))) float f32x2;
typedef __attribute__((ext_vector_type(4))) float f32x4;
typedef __attribute__((ext_vector_type(4))) u32 u32x4;
typedef __attribute__((ext_vector_type(8))) _Float16 f16x8;

__device__ __forceinline__ f32x2 pk_add(f32x2 a, f32x2 b) {
    f32x2 d; asm("v_pk_add_f32 %0, %1, %2" : "=v"(d) : "v"(a), "v"(b)); return d;
}
__device__ __forceinline__ f32x2 pk_fma(f32x2 a, f32x2 b, f32x2 c) {
    f32x2 d; asm("v_pk_fma_f32 %0, %1, %2, %3" : "=v"(d) : "v"(a), "v"(b), "v"(c)); return d;
}
__device__ __forceinline__ u32 pkrtz(float a, float b) {
    u32 d; asm("v_cvt_pkrtz_f16_f32 %0, %1, %2" : "=v"(d) : "v"(a), "v"(b)); return d;
}
__device__ __forceinline__ float fast_sigmoid(float z) {
    float e, p;
    asm("v_exp_f32 %0, %1" : "=v"(e) : "v"(-z * 1.44269504f));
    asm("v_rcp_f32 %0, %1" : "=v"(p) : "v"(1.f + e));
    return p;
}

// ---------------- embed: x -> emb -> ai, aj (exact) + ai256, ajb256 ---------
__global__ void __launch_bounds__(256) k_embed(
    const float* __restrict__ x, const float* __restrict__ w_emb,
    const float* __restrict__ b_emb, const float* __restrict__ w_proj,
    const float* __restrict__ b_proj, const float* __restrict__ w1,
    const float* __restrict__ b1,
    float* __restrict__ ai, float* __restrict__ aj,
    float* __restrict__ ai256, float* __restrict__ ajb256) {
    __shared__ float sh[4][64];
    __shared__ float se[4][64];
    const int c = threadIdx.x;        // 0..63
    const int lr = threadIdx.y;       // 0..3
    const int row = blockIdx.x * 4 + lr;
    const float xv = x[row];
    sh[lr][c] = fmaxf(fmaf(xv, w_emb[c], b_emb[c]), 0.f);
    __syncthreads();
    float e = 0.f;
#pragma unroll
    for (int h = 0; h < 64; ++h) e = fmaf(sh[lr][h], w_proj[h * 64 + c], e);
    se[lr][c] = e + b_proj[c];
    __syncthreads();
    float a0 = 0.f, a1 = 0.f;
#pragma unroll
    for (int h = 0; h < 64; ++h) {
        const float ev = se[lr][h];
        a0 = fmaf(ev, w1[h * 64 + c], a0);
        a1 = fmaf(ev, w1[(64 + h) * 64 + c], a1);
    }
    ai[row * 64 + c] = a0;
    aj[row * 64 + c] = a1;
    ai256[row * 64 + c] = a0 * 256.0f;                 // exact (pow2)
    ajb256[row * 64 + c] = (a1 + b1[c]) * 256.0f;
}

// ---------------- fused pair scorer + symmetrize + hist8 --------------------
__global__ void __launch_bounds__(256) k_pairs_sym(
    const float* __restrict__ ai256, const float* __restrict__ ajb256,
    const float* __restrict__ w2, const float* __restrict__ b2,
    const float* __restrict__ w3, const float* __restrict__ b3,
    float* __restrict__ probs, u32* __restrict__ hist8) {
    __shared__ float sI[2048];        // ai256 rows I0 (32 x 64)
    __shared__ float sJ[2048];        // ai256 rows J0
    __shared__ float sp1[32 * 33];    // sigma(s(i,j)) at [ii][jj], stride 33
    __shared__ float sp2[32 * 33];    // sigma(s(j,i)) at [ii][jj]
    __shared__ u32 lh[1024];          // 4-replica 256-bin hist
    const int tid = threadIdx.x;
    const int b = blockIdx.y;
    int remb = blockIdx.x, ta = 0;
    while (remb >= 16 - ta) { remb -= 16 - ta; ++ta; }
    const int tb = ta + remb;         // ta <= tb
    const int i0 = ta << 5, j0 = tb << 5;
    {
        const int r = tid >> 3, c8v = (tid & 7) << 3;
        const float* srcI = &ai256[(((b << 9) + i0 + r) << 6) + c8v];
        *(float4*)&sI[(r << 6) + c8v]     = *(const float4*)&srcI[0];
        *(float4*)&sI[(r << 6) + c8v + 4] = *(const float4*)&srcI[4];
        const float* srcJ = &ai256[(((b << 9) + j0 + r) << 6) + c8v];
        *(float4*)&sJ[(r << 6) + c8v]     = *(const float4*)&srcJ[0];
        *(float4*)&sJ[(r << 6) + c8v + 4] = *(const float4*)&srcJ[4];
        lh[tid] = 0; lh[256 + tid] = 0; lh[512 + tid] = 0; lh[768 + tid] = 0;
    }
    const int lane = tid & 63;
    const int lp = lane & 15, lg = lane >> 4;
    const int wave = tid >> 6;
    const int dir = wave >> 1, wc = wave & 1;
    const int colb = (wc << 4) + lp;                 // 0..31 within tile
    const int colg = (dir ? i0 : j0) + colb;         // global col row-index

    alignas(16) float ajr[2][8];
    {
        const float* base = &ajb256[(((b << 9) + colg) << 6) + (lg << 3)];
        *(float4*)&ajr[0][0] = *(const float4*)&base[0];
        *(float4*)&ajr[0][4] = *(const float4*)&base[4];
        *(float4*)&ajr[1][0] = *(const float4*)&base[32];
        *(float4*)&ajr[1][4] = *(const float4*)&base[36];
    }
    f16x8 Ah[2][2], Al[2][2];         // w2^T hi / lo*2048 [ktile][hchunk]
#pragma unroll
    for (int kt = 0; kt < 2; ++kt)
#pragma unroll
        for (int ch = 0; ch < 2; ++ch)
#pragma unroll
            for (int e = 0; e < 8; ++e) {
                const float wv2 = w2[((ch << 5) + (lg << 3) + e) * 32 + (kt << 4) + lp];
                const _Float16 wh = (_Float16)wv2;
                Ah[kt][ch][e] = wh;
                Al[kt][ch][e] = (_Float16)((wv2 - (float)wh) * 2048.0f);
            }
    float b2f[2][4], w3f[2][4];
#pragma unroll
    for (int kt = 0; kt < 2; ++kt)
#pragma unroll
        for (int r = 0; r < 4; ++r) {
            b2f[kt][r] = b2[(kt << 4) + (lg << 2) + r] * 256.0f;
            w3f[kt][r] = w3[(kt << 4) + (lg << 2) + r] * 0.00390625f;
        }
    const float b3v = b3[0];
    __syncthreads();

    const float* __restrict__ sA = dir ? sJ : sI;
    float* __restrict__ spO = dir ? sp2 : sp1;
    const f32x2 CN1 = {-1.f, -1.f};

    for (int r = 0; r < 32; ++r) {
        alignas(16) float ar[2][8];
        *(float4*)&ar[0][0] = *(const float4*)&sA[(r << 6) + (lg << 3)];
        *(float4*)&ar[0][4] = *(const float4*)&sA[(r << 6) + (lg << 3) + 4];
        *(float4*)&ar[1][0] = *(const float4*)&sA[(r << 6) + 32 + (lg << 3)];
        *(float4*)&ar[1][4] = *(const float4*)&sA[(r << 6) + 32 + (lg << 3) + 4];
        alignas(16) u32 hw[2][4], lw[2][4];
#pragma unroll
        for (int c = 0; c < 2; ++c)
#pragma unroll
            for (int e2 = 0; e2 < 4; ++e2) {
                const f32x2 a2 = *(const f32x2*)&ar[c][e2 * 2];
                const f32x2 j2 = *(const f32x2*)&ajr[c][e2 * 2];
                f32x2 u2 = pk_add(a2, j2);
                u2[0] = fmaxf(u2[0], 0.f);
                u2[1] = fmaxf(u2[1], 0.f);
                hw[c][e2] = pkrtz(u2[0], u2[1]);
                f32x2 hif;
                hif[0] = __uint_as_float(__float_as_uint(u2[0]) & 0xFFFFE000u);
                hif[1] = __uint_as_float(__float_as_uint(u2[1]) & 0xFFFFE000u);
                const f32x2 lo = pk_fma(hif, CN1, u2);   // exact residual
                lw[c][e2] = pkrtz(lo[0], lo[1]);
            }
        const f16x8 Bh0 = __builtin_bit_cast(f16x8, *(u32x4*)&hw[0][0]);
        const f16x8 Bh1 = __builtin_bit_cast(f16x8, *(u32x4*)&hw[1][0]);
        const f16x8 Bl0 = __builtin_bit_cast(f16x8, *(u32x4*)&lw[0][0]);
        const f16x8 Bl1 = __builtin_bit_cast(f16x8, *(u32x4*)&lw[1][0]);
        // main acc (scale 2^8): wh*th + wh*tl ; c acc (scale 2^19): wl*th
        f32x4 am0 = {0.f,0.f,0.f,0.f}, am1 = {0.f,0.f,0.f,0.f};
        f32x4 ac0 = {0.f,0.f,0.f,0.f}, ac1 = {0.f,0.f,0.f,0.f};
        am0 = __builtin_amdgcn_mfma_f32_16x16x32_f16(Ah[0][0], Bh0, am0, 0, 0, 0);
        am0 = __builtin_amdgcn_mfma_f32_16x16x32_f16(Ah[0][1], Bh1, am0, 0, 0, 0);
        am0 = __builtin_amdgcn_mfma_f32_16x16x32_f16(Ah[0][0], Bl0, am0, 0, 0, 0);
        am0 = __builtin_amdgcn_mfma_f32_16x16x32_f16(Ah[0][1], Bl1, am0, 0, 0, 0);
        ac0 = __builtin_amdgcn_mfma_f32_16x16x32_f16(Al[0][0], Bh0, ac0, 0, 0, 0);
        ac0 = __builtin_amdgcn_mfma_f32_16x16x32_f16(Al[0][1], Bh1, ac0, 0, 0, 0);
        am1 = __builtin_amdgcn_mfma_f32_16x16x32_f16(Ah[1][0], Bh0, am1, 0, 0, 0);
        am1 = __builtin_amdgcn_mfma_f32_16x16x32_f16(Ah[1][1], Bh1, am1, 0, 0, 0);
        am1 = __builtin_amdgcn_mfma_f32_16x16x32_f16(Ah[1][0], Bl0, am1, 0, 0, 0);
        am1 = __builtin_amdgcn_mfma_f32_16x16x32_f16(Ah[1][1], Bl1, am1, 0, 0, 0);
        ac1 = __builtin_amdgcn_mfma_f32_16x16x32_f16(Al[1][0], Bh0, ac1, 0, 0, 0);
        ac1 = __builtin_amdgcn_mfma_f32_16x16x32_f16(Al[1][1], Bh1, ac1, 0, 0, 0);
        float s = 0.f;
#pragma unroll
        for (int q = 0; q < 4; ++q) {
            const float amc = fmaf(ac0[q], 4.8828125e-4f, am0[q]);   // + c*2^-11
            s = fmaf(fmaxf(amc + b2f[0][q], 0.f), w3f[0][q], s);
        }
#pragma unroll
        for (int q = 0; q < 4; ++q) {
            const float amc = fmaf(ac1[q], 4.8828125e-4f, am1[q]);
            s = fmaf(fmaxf(amc + b2f[1][q], 0.f), w3f[1][q], s);
        }
        s += __shfl_xor(s, 16);
        s += __shfl_xor(s, 32);
        const float p = fast_sigmoid(s + b3v);
        if (lane < 16) {
            if (dir == 0) spO[r * 33 + colb] = p;     // sigma(s(i0+r, j0+colb))
            else          spO[colb * 33 + r] = p;     // sigma(s(j0+r, i0+colb))
        }
    }
    __syncthreads();

    // average, diag-zero, write both tiles, histogram
    {
        const int pr = tid >> 3;              // ii
        const int pc = (tid & 7) << 2;        // jj0
        const int rep = (tid & 3) << 8;
        const bool diag = (ta == tb);
        float4 vo;
        float vq[4];
#pragma unroll
        for (int q = 0; q < 4; ++q) {
            float v = 0.5f * (sp1[pr * 33 + pc + q] + sp2[pr * 33 + pc + q]);
            if (diag && pr == pc + q) v = 0.f;
            vq[q] = v;
            atomicAdd(&lh[rep + (__float_as_uint(v) >> 24)], diag ? 1u : 2u);
        }
        vo.x = vq[0]; vo.y = vq[1]; vo.z = vq[2]; vo.w = vq[3];
        *(float4*)&probs[(((b << 9) + i0 + pr) << 9) + j0 + pc] = vo;
        if (!diag) {
            float4 w4;
            w4.x = 0.5f * (sp1[(pc + 0) * 33 + pr] + sp2[(pc + 0) * 33 + pr]);
            w4.y = 0.5f * (sp1[(pc + 1) * 33 + pr] + sp2[(pc + 1) * 33 + pr]);
            w4.z = 0.5f * (sp1[(pc + 2) * 33 + pr] + sp2[(pc + 2) * 33 + pr]);
            w4.w = 0.5f * (sp1[(pc + 3) * 33 + pr] + sp2[(pc + 3) * 33 + pr]);
            *(float4*)&probs[(((b << 9) + j0 + pr) << 9) + i0 + pc] = w4;
        }
    }
    __syncthreads();
    const u32 sum = lh[tid] + lh[256 + tid] + lh[512 + tid] + lh[768 + tid];
    if (sum) atomicAdd(&hist8[b * 256 + tid], sum);
}

// ---------------- 13-bit filtered LDS histogram (derives c8 in-block) -------
__global__ void __launch_bounds__(256) k_hist13(
    const float* __restrict__ probs, const u32* __restrict__ hist8,
    u32* __restrict__ hist13) {
    __shared__ u32 lh[8192];
    __shared__ u32 s8[256];
    __shared__ u32 selsh;
    const int t = threadIdx.x;
    const int b = blockIdx.y;
    for (int k = t; k < 8192; k += 256) lh[k] = 0u;
    s8[t] = hist8[b * 256 + t];
    __syncthreads();
    for (int off = 1; off < 256; off <<= 1) {   // inclusive suffix sums
        const u32 v = (t + off < 256) ? s8[t + off] : 0u;
        __syncthreads();
        s8[t] += v;
        __syncthreads();
    }
    {
        const u32 above = (t < 255) ? s8[t + 1] : 0u;
        if (s8[t] >= (u32)KSEL && above < (u32)KSEL) selsh = (u32)t;
    }
    __syncthreads();
    const u32 sel = selsh;
    const float* Pb = probs + b * NNv;
    const int base = blockIdx.x * 4096 + t * 4;
#pragma unroll
    for (int e = 0; e < 4; ++e) {
        const float4 v4 = *(const float4*)&Pb[base + e * 1024];
        const float vv[4] = {v4.x, v4.y, v4.z, v4.w};
#pragma unroll
        for (int q = 0; q < 4; ++q) {
            const u32 key = __float_as_uint(vv[q]);
            if ((key >> 24) == sel) atomicAdd(&lh[(key >> 11) & 8191u], 1u);
        }
    }
    __syncthreads();
    for (int k = t; k < 8192; k += 256) {
        const u32 v = lh[k];
        if (v) atomicAdd(&hist13[b * 8192 + k], v);
    }
}

// ---------------- 13-bit select -> Tlo/Thi (derives c8+rem in-block) --------
__global__ void __launch_bounds__(256) k_sel13(
    const u32* __restrict__ hist8, const u32* __restrict__ hist13,
    float* __restrict__ thr) {
    __shared__ u32 s8[256];
    __shared__ u32 s[256];
    __shared__ u32 c8sh, remsh;
    const int b = blockIdx.x, t = threadIdx.x;
    s8[t] = hist8[b * 256 + t];
    __syncthreads();
    for (int off = 1; off < 256; off <<= 1) {
        const u32 v = (t + off < 256) ? s8[t + off] : 0u;
        __syncthreads();
        s8[t] += v;
        __syncthreads();
    }
    {
        const u32 above = (t < 255) ? s8[t + 1] : 0u;
        if (s8[t] >= (u32)KSEL && above < (u32)KSEL) {
            c8sh = (u32)t;
            remsh = (u32)KSEL - above;
        }
    }
    __syncthreads();
    const u32 c8 = c8sh, remv = remsh;
    const u32* H = hist13 + b * 8192;
    u32 sum = 0;
    for (int k = 0; k < 32; ++k) sum += H[t * 32 + k];
    s[t] = sum;
    __syncthreads();
    for (int off = 1; off < 256; off <<= 1) {   // inclusive suffix sums
        const u32 v = (t + off < 256) ? s[t + off] : 0u;
        __syncthreads();
        s[t] += v;
        __syncthreads();
    }
    const u32 above = (t < 255) ? s[t + 1] : 0u;
    if (s[t] >= remv && above < remv) {
        u32 cum = above;
        int c = 31;
        for (; c >= 0; --c) {
            cum += H[t * 32 + c];
            if (cum >= remv) break;
        }
        const u32 p21 = (c8 << 13) | (u32)(t * 32 + c);
        thr[b]     = __uint_as_float(p21 << 11) - 2.f * DELTA;        // Tlo
        thr[8 + b] = __uint_as_float((p21 + 1u) << 11) + 2.f * DELTA; // Thi
    }
}

// ---------------- band collect (pure, no exact) -----------------------------
__global__ void __launch_bounds__(256) k_band(
    const float* __restrict__ P, const float* __restrict__ thr,
    u32* __restrict__ C_in, u32* __restrict__ bandCnt, u32* __restrict__ bandIdx,
    u32* __restrict__ bgt) {
    __shared__ u32 lidx[2048];
    __shared__ u32 lcnt, lhi, gbase;
    const int b = blockIdx.y, blk = blockIdx.x, t = threadIdx.x;
    if (t == 0) { lcnt = 0u; lhi = 0u; }
    __syncthreads();
    const float Tlo = thr[b], Thi = thr[8 + b];
    const int fi0 = blk * 1024 + t * 4;
    const float4 v = *(const float4*)&P[b * NNv + fi0];
    const float vv[4] = {v.x, v.y, v.z, v.w};
    u32 hc = 0;
#pragma unroll
    for (int q = 0; q < 4; ++q) {
        const float xq = vv[q];
        if (xq > Thi) ++hc;
        else if (xq >= Tlo) {
            const u32 p = atomicAdd(&lcnt, 1u);
            if (p < 2048u) lidx[p] = (u32)(fi0 + q);
        }
    }
    if (hc) atomicAdd(&lhi, hc);
    __syncthreads();
    const u32 ln = min(lcnt, 2048u);
    if (t == 0) {
        bgt[b * 256 + blk] = lhi;
        if (lhi) atomicAdd(&C_in[b], lhi);
        gbase = ln ? atomicAdd(&bandCnt[b], ln) : 0u;
    }
    __syncthreads();
    for (u32 p = t; p < ln; p += 256) {
        const u32 g = gbase + p;
        if (g < (u32)CAPB) bandIdx[b * CAPB + g] = lidx[p];
    }
}

// ---------------- exact scorer (bit-identical to R1 arithmetic) -------------
__device__ __forceinline__ float exact_p(const float* __restrict__ rai,
                                         const float* __restrict__ raj,
                                         const float* __restrict__ s_w2,
                                         const float* __restrict__ s_b1,
                                         const float* __restrict__ s_b2,
                                         const float* __restrict__ s_w3,
                                         float b3v) {
    float acc[32];
#pragma unroll
    for (int k = 0; k < 32; ++k) acc[k] = 0.f;
#pragma unroll 1
    for (int h0 = 0; h0 < 64; h0 += 16) {
        float A[16], J[16];
#pragma unroll
        for (int q = 0; q < 4; ++q) {
            *(float4*)&A[q * 4] = *(const float4*)&rai[h0 + q * 4];
            *(float4*)&J[q * 4] = *(const float4*)&raj[h0 + q * 4];
        }
#pragma unroll
        for (int hh = 0; hh < 16; ++hh) {
            const float tv = fmaxf((A[hh] + J[hh]) + s_b1[h0 + hh], 0.f);
#pragma unroll
            for (int k = 0; k < 32; ++k) acc[k] = fmaf(tv, s_w2[(h0 + hh) * 32 + k], acc[k]);
        }
    }
    float d = 0.f;
#pragma unroll
    for (int k = 0; k < 32; ++k) d = fmaf(fmaxf(acc[k] + s_b2[k], 0.f), s_w3[k], d);
    return 1.f / (1.f + expf(-(d + b3v)));
}

// ---------------- dense exact recompute of band pairs -----------------------
__global__ void __launch_bounds__(256) k_band_exact(
    const float* __restrict__ ai, const float* __restrict__ aj,
    const float* __restrict__ b1, const float* __restrict__ w2,
    const float* __restrict__ b2, const float* __restrict__ w3,
    const float* __restrict__ b3, const u32* __restrict__ bandCnt,
    const u32* __restrict__ bandIdx, float* __restrict__ bandVal) {
    __shared__ float s_w2[2048];
    __shared__ float s_b1[64], s_b2[32], s_w3[32];
    const int b = blockIdx.y, t = threadIdx.x;
    {
        const int o = t * 8;
        *(float4*)&s_w2[o]     = *(const float4*)&w2[o];
        *(float4*)&s_w2[o + 4] = *(const float4*)&w2[o + 4];
        if (t < 64) s_b1[t] = b1[t];
        if (t < 32) { s_b2[t] = b2[t]; s_w3[t] = w3[t]; }
    }
    __syncthreads();
    const u32 nb = min(bandCnt[b], (u32)CAPB);
    const float b3v = b3[0];
    for (u32 e = blockIdx.x * 256 + t; e < nb; e += 8192) {
        const u32 idx = bandIdx[b * CAPB + e];
        const int i = (int)(idx >> 9), j = (int)(idx & 511u);
        const float* ri  = &ai[(((b << 9) + i)) << 6];
        const float* rj  = &aj[(((b << 9) + j)) << 6];
        const float* rj2 = &ai[(((b << 9) + j)) << 6];
        const float* ri2 = &aj[(((b << 9) + i)) << 6];
        const float p1 = exact_p(ri, rj, s_w2, s_b1, s_b2, s_w3, b3v);   // P[i][j]
        const float p2 = exact_p(rj2, ri2, s_w2, s_b1, s_b2, s_w3, b3v); // P[j][i]
        bandVal[b * CAPB + e] = 0.5f * (p1 + p2);
    }
}

// ---------------- band select + fused per-block counts + scan ---------------
__global__ void __launch_bounds__(256) k_band_select(
    const u32* __restrict__ bandCnt, const u32* __restrict__ C_in,
    const u32* __restrict__ bandIdx, const float* __restrict__ bandVal,
    u32* __restrict__ bitmap, const u32* __restrict__ bgt,
    u32* __restrict__ goff) {
    __shared__ u32 red[256];
    __shared__ u32 lsel[256];
    __shared__ u32 tie[8192];
    __shared__ u32 tieCnt;
    const int b = blockIdx.x, t = threadIdx.x;
    const u32 nb = min(bandCnt[b], (u32)CAPB);
    const u32 Kp = (u32)KSEL - C_in[b];
    const u32* vb = (const u32*)(bandVal + b * CAPB);
    const u32* ib = bandIdx + b * CAPB;
    u32* bm = bitmap + b * 8192;
    lsel[t] = 0u;
    u32 mn = 0xFFFFFFFFu, mx = 0u;
    for (u32 k = t; k < nb; k += 256) { const u32 v = vb[k]; mn = min(mn, v); mx = max(mx, v); }
    red[t] = mn; __syncthreads();
    for (int s = 128; s > 0; s >>= 1) { if (t < s) red[t] = min(red[t], red[t + s]); __syncthreads(); }
    const u32 glo = red[0]; __syncthreads();
    red[t] = mx; __syncthreads();
    for (int s = 128; s > 0; s >>= 1) { if (t < s) red[t] = max(red[t], red[t + s]); __syncthreads(); }
    const u32 ghi = red[0]; __syncthreads();
    u32 lo = glo, hi = ghi;
    while (lo < hi) {
        const u32 mid = lo + ((hi - lo) >> 1);
        u32 c = 0;
        for (u32 k = t; k < nb; k += 256) c += (vb[k] > mid);
        red[t] = c; __syncthreads();
        for (int s = 128; s > 0; s >>= 1) { if (t < s) red[t] += red[t + s]; __syncthreads(); }
        const u32 tot = red[0]; __syncthreads();
        if (tot >= Kp) lo = mid + 1; else hi = mid;
    }
    const u32 Tx = lo;
    if (t == 0) tieCnt = 0u;
    __syncthreads();
    u32 c = 0;
    for (u32 k = t; k < nb; k += 256) {
        const u32 v = vb[k];
        if (v > Tx) {
            ++c;
            const u32 idx = ib[k];
            atomicOr(&bm[idx >> 5], 1u << (idx & 31u));
            atomicAdd(&lsel[idx >> 10], 1u);
        } else if (v == Tx) {
            const u32 p = atomicAdd(&tieCnt, 1u);
            if (p < 8192u) tie[p] = ib[k];
        }
    }
    red[t] = c; __syncthreads();
    for (int s = 128; s > 0; s >>= 1) { if (t < s) red[t] += red[t + s]; __syncthreads(); }
    const u32 Ap = red[0]; __syncthreads();
    const u32 Rp = Kp - Ap;
    const u32 E = min(tieCnt, 8192u);
    for (u32 k = t; k < E; k += 256) {
        const u32 my = tie[k];
        u32 r = 0;
        for (u32 m = 0; m < E; ++m) r += (tie[m] < my);
        if (r < Rp) {
            atomicOr(&bm[my >> 5], 1u << (my & 31u));
            atomicAdd(&lsel[my >> 10], 1u);
        }
    }
    __syncthreads();
    // fused exclusive scan of (bgt + lsel) -> goff
    const u32 g = bgt[b * 256 + t] + lsel[t];
    red[t] = g;
    __syncthreads();
    for (int off = 1; off < 256; off <<= 1) {
        const u32 a = (t >= off) ? red[t - off] : 0u;
        __syncthreads();
        red[t] += a;
        __syncthreads();
    }
    goff[b * 256 + t] = red[t] - g;
}

// ---------------- write ------------------------------------------------------
__global__ void k_write(const float* __restrict__ P, const float* __restrict__ thr,
                        const u32* __restrict__ bitmap, const u32* __restrict__ goff,
                        float* __restrict__ out) {
    __shared__ u32 sg[256];
    const int b = blockIdx.y, blk = blockIdx.x, t = threadIdx.x;
    const float Thi = thr[8 + b];
    const int pbase = b * NNv;
    const int fi0 = blk * 1024 + t * 4;
    const float4 v = *(const float4*)&P[pbase + fi0];
    const float vv[4] = {v.x, v.y, v.z, v.w};
    const u32 w = bitmap[b * 8192 + (fi0 >> 5)];
    const u32 sh = (u32)(fi0 & 31);
    bool sel[4];
    u32 cnt = 0;
#pragma unroll
    for (int q = 0; q < 4; ++q) {
        sel[q] = (vv[q] > Thi) || ((w >> (sh + q)) & 1u);
        cnt += sel[q];
    }
    sg[t] = cnt;
    __syncthreads();
    for (int off = 1; off < 256; off <<= 1) {
        const u32 a = (t >= off) ? sg[t - off] : 0u;
        __syncthreads();
        sg[t] += a;
        __syncthreads();
    }
    u32 pos = goff[b * 256 + blk] + sg[t] - cnt;
#pragma unroll
    for (int q = 0; q < 4; ++q) {
        if (sel[q]) {
            if (pos < (u32)KSEL) {
                const int g = b * KSEL + (int)pos;
                const int fi = fi0 + q;
                const int row = fi >> 9, col = fi & 511;
                out[g]           = (float)(row + (b << 9));
                out[BKv + g]     = (float)(col + (b << 9));
                out[2 * BKv + g] = vv[q];
                out[3 * BKv + pbase + fi] = vv[q];
            }
            ++pos;
        }
    }
}

// ---------------------------------------------------------------------------
extern "C" void kernel_launch(void* const* d_in, const int* in_sizes, int n_in,
                              void* d_out, int out_size, void* d_ws, size_t ws_size,
                              hipStream_t stream) {
    const float* x      = (const float*)d_in[0];
    const float* w_emb  = (const float*)d_in[1];
    const float* b_emb  = (const float*)d_in[2];
    const float* w_proj = (const float*)d_in[3];
    const float* b_proj = (const float*)d_in[4];
    const float* w1     = (const float*)d_in[5];
    const float* b1     = (const float*)d_in[6];
    const float* w2     = (const float*)d_in[7];
    const float* b2     = (const float*)d_in[8];
    const float* w3     = (const float*)d_in[9];
    const float* b3     = (const float*)d_in[10];
    (void)in_sizes; (void)n_in; (void)ws_size;

    char* ws = (char*)d_ws;
    float* ai      = (float*)(ws);                    // 1 MiB
    float* aj      = (float*)(ws + 1048576);          // 1 MiB
    float* ai256   = (float*)(ws + 2097152);          // 1 MiB
    float* ajb256  = (float*)(ws + 3145728);          // 1 MiB
    float* probs   = (float*)(ws + 4194304);          // 8 MiB
    u32*   bandIdx = (u32*)  (ws + 12582912);         // 1 MiB
    float* bandVal = (float*)(ws + 13631488);         // 1 MiB
    const size_t SOFF = 14680064;
    u32*   hist8   = (u32*)  (ws + SOFF);             // 8 KiB   [zeroed]
    u32*   hist13  = (u32*)  (ws + SOFF + 8192);      // 256 KiB [zeroed]
    float* thr     = (float*)(ws + SOFF + 270336);    // 64 B
    u32*   C_in    = (u32*)  (ws + SOFF + 270400);    //          [zeroed]
    u32*   bandCnt = (u32*)  (ws + SOFF + 270432);    //          [zeroed]
    u32*   bitmap  = (u32*)  (ws + SOFF + 270464);    // 256 KiB [zeroed]
    u32*   bgt     = (u32*)  (ws + SOFF + 532608);    // 8 KiB (fully written)
    u32*   goff    = (u32*)  (ws + SOFF + 540800);    // 8 KiB (fully written)

    float* out = (float*)d_out;

    hipMemsetAsync(d_out, 0, (size_t)out_size * sizeof(float), stream);
    hipMemsetAsync(ws + SOFF, 0, 532608, stream);     // hist8..bitmap

    k_embed<<<1024, dim3(64, 4, 1), 0, stream>>>(x, w_emb, b_emb, w_proj, b_proj,
                                                 w1, b1, ai, aj, ai256, ajb256);
    k_pairs_sym<<<dim3(136, 8), 256, 0, stream>>>(ai256, ajb256, w2, b2, w3, b3,
                                                  probs, hist8);
    k_hist13<<<dim3(64, 8), 256, 0, stream>>>(probs, hist8, hist13);
    k_sel13<<<8, 256, 0, stream>>>(hist8, hist13, thr);
    k_band<<<dim3(256, 8), 256, 0, stream>>>(probs, thr, C_in, bandCnt, bandIdx, bgt);
    k_band_exact<<<dim3(32, 8), 256, 0, stream>>>(ai, aj, b1, w2, b2, w3, b3,
                                                  bandCnt, bandIdx, bandVal);
    k_band_select<<<8, 256, 0, stream>>>(bandCnt, C_in, bandIdx, bandVal,
                                         bitmap, bgt, goff);
    k_write<<<dim3(256, 8), 256, 0, stream>>>(probs, thr, bitmap, goff, out);
}